// Round 7
// baseline (660.778 us; speedup 1.0000x reference)
//
#include <hip/hip_runtime.h>
#include <hip/hip_bf16.h>

#define BN_EPS 1e-5f
constexpr int C = 256;

typedef __attribute__((ext_vector_type(8))) short bf16x8;
typedef __attribute__((ext_vector_type(4))) float f32x4;

static __device__ __forceinline__ unsigned short f2bf(float f) {
    __hip_bfloat16 h = __float2bfloat16(f);
    return *reinterpret_cast<unsigned short*>(&h);
}
static __device__ __forceinline__ float bf2f(unsigned short u) {
    unsigned int v = ((unsigned int)u) << 16;
    return __uint_as_float(v);
}

// Fold BN scale into weights, transpose [N][C][9] f32 -> [9][N][C] bf16.
__global__ __launch_bounds__(256) void wprep(
    const float* __restrict__ w, const float* __restrict__ gamma,
    const float* __restrict__ var, unsigned short* __restrict__ wt)
{
    const int n = blockIdx.x, c = threadIdx.x;
    const float scale = gamma[n] * rsqrtf(var[n] + BN_EPS);
    const float* wp = w + ((size_t)n * C + c) * 9;
#pragma unroll
    for (int k = 0; k < 9; ++k)
        wt[((size_t)k * C + n) * C + c] = f2bf(wp[k] * scale);
}

// fp32 NCHW [g][C][HW] -> bf16 [g][HW][C] (pixel-major, channel-contiguous).
template<int HW>
__global__ __launch_bounds__(256) void nchw_to_pc(
    const float* __restrict__ in, unsigned short* __restrict__ out)
{
    __shared__ float s_t[64][65];
    const int b = blockIdx.z, c0 = blockIdx.y * 64, px0 = blockIdx.x * 64;
    const int t = threadIdx.x;
    const float* ip = in + ((size_t)b * C + c0) * HW;

#pragma unroll
    for (int it = 0; it < 4; ++it) {
        int i = t + it * 256;
        int cl = i >> 4, q = i & 15;
#pragma unroll
        for (int j = 0; j < 4; ++j) {
            int p = px0 + q * 4 + j;
            s_t[cl][q * 4 + j] = (p < HW) ? ip[(size_t)cl * HW + p] : 0.f;
        }
    }
    __syncthreads();

    unsigned short* op = out + (size_t)b * HW * C + (size_t)px0 * C + c0;
#pragma unroll
    for (int it = 0; it < 2; ++it) {
        int i = t + it * 256;
        int pl = i >> 3, gq = i & 7;
        if (px0 + pl < HW) {
            bf16x8 pk;
#pragma unroll
            for (int u = 0; u < 8; ++u)
                pk[u] = (short)f2bf(s_t[gq * 8 + u][pl]);
            *(bf16x8*)&op[(size_t)pl * C + gq * 8] = pk;
        }
    }
}

// ---------------------------------------------------------------------------
// SEARCH CONV v3: 31x31 -> 29x29 implicit-GEMM bf16 MFMA.
// A: fragments loaded DIRECTLY from global [g][961][256] (L1-resident window,
//    1-tap-ahead register prefetch). No A LDS at all.
// B: weights [9][256][256] in LDS, double-buffered per tap-step, staged with
//    nontemporal loads (keep L1 for A). One barrier per step.
// Block: 512 thr = 8 waves (2 wm x 4 wn). BM=224, BN=256, wave tile 112x64.
// ---------------------------------------------------------------------------
__global__ __launch_bounds__(512, 2) void sconv_mfma(
    const unsigned short* __restrict__ in,   // [g][961][256] bf16
    const unsigned short* __restrict__ wt,   // [9][256][256] bf16
    const float* __restrict__ gamma, const float* __restrict__ beta,
    const float* __restrict__ mean, const float* __restrict__ var,
    unsigned short* __restrict__ outp)       // [g][256][844] bf16
{
    constexpr int WOUT = 29, NPOS = 841;
    constexpr int BM = 224, MF = 7, NF = 4;
    constexpr int LDK = 40;                  // 32 ch + 8 pad (80B rows)
    constexpr int BBUF = 256 * LDK;          // shorts per B buffer
    constexpr int BIT = 2;                   // 256n*4slots / 512thr

    __shared__ __align__(16) short s_b[2 * BBUF];   // 40,960 B

    const int t = threadIdx.x;
    const int lane = t & 63, wave = t >> 6;
    const int wm = wave >> 2, wn = wave & 3;
    const int lr = lane >> 4, lc = lane & 15;

    const int p0 = blockIdx.x * BM;          // 0,224,448,672
    const int b  = blockIdx.y;

    const unsigned short* in_b = in + (size_t)b * (961 * 256);

    // A fragment base offsets (shorts): absolute pixel * 256 + lr*8
    int apix[MF];
#pragma unroll
    for (int m = 0; m < MF; ++m) {
        int pm = wm * 112 + m * 16 + lc;
        int p = p0 + pm; p = p < NPOS ? p : NPOS - 1;
        int y = p / WOUT, x = p - y * WOUT;
        apix[m] = (y * 31 + x) * 256 + lr * 8;
    }

    // B staging decomposition
    const unsigned short* bptr[BIT]; int boff[BIT];
#pragma unroll
    for (int it = 0; it < BIT; ++it) {
        int i = t + it * 512;
        int n = i >> 2, sl = i & 3;
        bptr[it] = wt + (size_t)n * 256 + sl * 8;
        boff[it] = n * LDK + sl * 8;
    }

    f32x4 acc[MF][NF];
#pragma unroll
    for (int m = 0; m < MF; ++m)
#pragma unroll
        for (int n = 0; n < NF; ++n) acc[m][n] = f32x4{0.f, 0.f, 0.f, 0.f};

    // prologue: B[tap0,c0=0] -> buf0; A frags for (tap0, c0=0)
    bf16x8 bstg[BIT];
#pragma unroll
    for (int it = 0; it < BIT; ++it)
        bstg[it] = __builtin_nontemporal_load((const bf16x8*)bptr[it]);
    bf16x8 af[MF];
#pragma unroll
    for (int m = 0; m < MF; ++m)
        af[m] = *(const bf16x8*)(in_b + apix[m]);
#pragma unroll
    for (int it = 0; it < BIT; ++it)
        *(bf16x8*)&s_b[boff[it]] = bstg[it];
    __syncthreads();

    int bsel = 0;
#pragma unroll 1
    for (int ch = 0; ch < 8; ++ch) {
        const int c0 = ch * 32;
#pragma unroll
        for (int tap = 0; tap < 9; ++tap) {
            const bool hasnext = (ch < 7) || (tap < 8);
            const int ntap = tap < 8 ? tap + 1 : 0;
            const int nc0 = tap < 8 ? c0 : c0 + 32;
            const int ndt = (ntap / 3) * 31 + (ntap % 3);   // next tap pixel offset

            // issue next-step B loads (nontemporal, land during MFMAs)
            bf16x8 afn[MF];
            if (hasnext) {
#pragma unroll
                for (int it = 0; it < BIT; ++it)
                    bstg[it] = __builtin_nontemporal_load(
                        (const bf16x8*)(bptr[it] + (size_t)ntap * 65536 + nc0));
                // issue next-tap A loads (L1-resident window)
#pragma unroll
                for (int m = 0; m < MF; ++m)
                    afn[m] = *(const bf16x8*)(in_b + apix[m] + ndt * 256 + nc0);
            }

            // B fragments from LDS
            bf16x8 bfr[NF];
#pragma unroll
            for (int n = 0; n < NF; ++n)
                bfr[n] = *(const bf16x8*)&s_b[bsel * BBUF + (wn * 64 + n * 16 + lc) * LDK + lr * 8];

            __builtin_amdgcn_s_setprio(1);
#pragma unroll
            for (int m = 0; m < MF; ++m)
#pragma unroll
                for (int n = 0; n < NF; ++n)
                    acc[m][n] = __builtin_amdgcn_mfma_f32_16x16x32_bf16(
                        af[m], bfr[n], acc[m][n], 0, 0, 0);
            __builtin_amdgcn_s_setprio(0);

            if (hasnext) {
#pragma unroll
                for (int it = 0; it < BIT; ++it)
                    *(bf16x8*)&s_b[(bsel ^ 1) * BBUF + boff[it]] = bstg[it];
#pragma unroll
                for (int m = 0; m < MF; ++m) af[m] = afn[m];
                __syncthreads();
            }
            bsel ^= 1;
        }
    }

    // epilogue: bias + relu -> bf16 planes (padded stride 844)
#pragma unroll
    for (int n = 0; n < NF; ++n) {
        const int co = wn * 64 + n * 16 + lc;
        const float sc = gamma[co] * rsqrtf(var[co] + BN_EPS);
        const float bias = beta[co] - mean[co] * sc;
#pragma unroll
        for (int m = 0; m < MF; ++m) {
            int pm = wm * 112 + m * 16 + lr * 4;
            int p = p0 + pm;
            f32x4 v = acc[m][n];
            float r0 = fmaxf(v.x + bias, 0.f);
            float r1 = fmaxf(v.y + bias, 0.f);
            float r2 = fmaxf(v.z + bias, 0.f);
            float r3 = fmaxf(v.w + bias, 0.f);
            unsigned short* op = outp + ((size_t)b * C + co) * 844 + p;
            if (p + 4 <= NPOS) {
                ushort4 pk;
                pk.x = f2bf(r0); pk.y = f2bf(r1); pk.z = f2bf(r2); pk.w = f2bf(r3);
                *(ushort4*)op = pk;
            } else {
                float rr[4] = {r0, r1, r2, r3};
#pragma unroll
                for (int i = 0; i < 4; ++i)
                    if (p + i < NPOS) op[i] = f2bf(rr[i]);
            }
        }
    }
}

// ---------------------------------------------------------------------------
// KERNEL CONV (small, 7x7 -> 5x5): B from global, A async-staged in LDS.
// ---------------------------------------------------------------------------
template<int HIN, int WOUT, int BPB, int BM, int BN_, int MF, int NF, bool OUT_BF16, int OSTRIDE>
__global__ __launch_bounds__(256, 3) void conv3_mfma(
    const unsigned short* __restrict__ in,
    const unsigned short* __restrict__ wt,
    const float* __restrict__ gamma, const float* __restrict__ beta,
    const float* __restrict__ mean, const float* __restrict__ var,
    void* __restrict__ outv)
{
    constexpr int WIN = HIN, HW = HIN * WIN;
    constexpr int NPOS = WOUT * WOUT;
    constexpr int PPB = BM / BPB;
    constexpr int NMT = (NPOS + PPB - 1) / PPB;
    constexpr int NR0 = (PPB - 1) / WOUT + 4;
    constexpr int NROWS = NR0 < HIN ? NR0 : HIN;
    constexpr int APIX = NROWS * WIN;
    constexpr int LDK = 40;
    constexpr int SLOTS_B = APIX * 4;
    constexpr int SLOTS = BPB * SLOTS_B;
    constexpr int ITERS = (SLOTS + 255) / 256;

    __shared__ __align__(16) short s_a[BPB * APIX * LDK];

    const int t = threadIdx.x;
    const int lane = t & 63, wave = t >> 6;
    const int wm = wave >> 1, wn = wave & 1;
    const int lr = lane >> 4, lc = lane & 15;

    const int mt = blockIdx.x % NMT, nt = blockIdx.x / NMT;
    const int p0 = mt * PPB, n0 = nt * BN_;
    const int b0 = blockIdx.y * BPB;
    const int y0 = p0 / WOUT;
    const int R = (HIN - y0) < NROWS ? (HIN - y0) : NROWS;
    const int npix = R * WIN;

    int arow[MF];
#pragma unroll
    for (int m = 0; m < MF; ++m) {
        int pm = wm * MF * 16 + m * 16 + lc;
        int bb = pm / PPB;
        int p = p0 + (pm % PPB);
        p = p < NPOS ? p : NPOS - 1;
        int y = p / WOUT, x = p % WOUT;
        arow[m] = (bb * APIX + (y - y0) * WIN + x) * LDK;
    }

    f32x4 acc[MF][NF];
#pragma unroll
    for (int m = 0; m < MF; ++m)
#pragma unroll
        for (int n = 0; n < NF; ++n) acc[m][n] = f32x4{0.f, 0.f, 0.f, 0.f};

    int sbb[ITERS], spx[ITERS], ssl[ITERS];
#pragma unroll
    for (int it = 0; it < ITERS; ++it) {
        int i = t + it * 256;
        int ii = i < SLOTS ? i : 0;
        int bb = (BPB == 1) ? 0 : (ii / SLOTS_B);
        int r = ii - bb * SLOTS_B;
        int px = r >> 2;
        sbb[it] = bb; spx[it] = px < npix ? px : 0; ssl[it] = r & 3;
    }

    const unsigned short* wb = wt + (size_t)(n0 + wn * (NF * 16) + lc) * C + lr * 8;

#define LOAD_STG(c0_)                                                          \
    _Pragma("unroll")                                                          \
    for (int it = 0; it < ITERS; ++it) {                                       \
        const unsigned short* sp =                                             \
            in + ((size_t)(b0 + sbb[it]) * HW + (size_t)(y0 * WIN + spx[it])) * C \
               + (c0_) + ssl[it] * 8;                                          \
        stg[it] = *(const bf16x8*)sp;                                          \
    }

#define WRITE_STG()                                                            \
    _Pragma("unroll")                                                          \
    for (int it = 0; it < ITERS; ++it)                                         \
        *(bf16x8*)&s_a[(sbb[it] * APIX + spx[it]) * LDK + ssl[it] * 8] = stg[it];

    {
        bf16x8 stg[ITERS];
        LOAD_STG(0)
        WRITE_STG()
    }

#pragma unroll 1
    for (int ch = 0; ch < 8; ++ch) {
        const int c0 = ch * 32;
        __syncthreads();

        bf16x8 stg[ITERS];
        if (ch < 7) { LOAD_STG(c0 + 32) }

        bf16x8 bcur[NF], bnxt[NF];
#pragma unroll
        for (int n = 0; n < NF; ++n)
            bnxt[n] = *(const bf16x8*)&wb[0 * (size_t)(C * C) + n * (16 * C) + c0];

#pragma unroll
        for (int tap = 0; tap < 9; ++tap) {
            const int dy = tap / 3, dx = tap % 3;
#pragma unroll
            for (int n = 0; n < NF; ++n) bcur[n] = bnxt[n];
            if (tap < 8) {
#pragma unroll
                for (int n = 0; n < NF; ++n)
                    bnxt[n] = *(const bf16x8*)&wb[(size_t)(tap + 1) * (C * C) + n * (16 * C) + c0];
            }
            bf16x8 af[MF];
#pragma unroll
            for (int m = 0; m < MF; ++m)
                af[m] = *(const bf16x8*)&s_a[arow[m] + (dy * WIN + dx) * LDK + lr * 8];
#pragma unroll
            for (int m = 0; m < MF; ++m)
#pragma unroll
                for (int n = 0; n < NF; ++n)
                    acc[m][n] = __builtin_amdgcn_mfma_f32_16x16x32_bf16(
                        af[m], bcur[n], acc[m][n], 0, 0, 0);
        }

        __syncthreads();
        if (ch < 7) { WRITE_STG() }
    }
#undef LOAD_STG
#undef WRITE_STG

#pragma unroll
    for (int n = 0; n < NF; ++n) {
        const int co = n0 + wn * NF * 16 + n * 16 + lc;
        const float sc = gamma[co] * rsqrtf(var[co] + BN_EPS);
        const float bias = beta[co] - mean[co] * sc;
#pragma unroll
        for (int m = 0; m < MF; ++m) {
            int pm = wm * MF * 16 + m * 16 + lr * 4;
            int bb = pm / PPB;
            int p = p0 + (pm % PPB);
            int b = b0 + bb;
            f32x4 v = acc[m][n];
            float r0 = fmaxf(v.x + bias, 0.f);
            float r1 = fmaxf(v.y + bias, 0.f);
            float r2 = fmaxf(v.z + bias, 0.f);
            float r3 = fmaxf(v.w + bias, 0.f);
            if (OUT_BF16) {
                unsigned short* op = (unsigned short*)outv + ((size_t)b * C + co) * OSTRIDE + p;
                if (p + 4 <= NPOS) {
                    ushort4 pk;
                    pk.x = f2bf(r0); pk.y = f2bf(r1); pk.z = f2bf(r2); pk.w = f2bf(r3);
                    *(ushort4*)op = pk;
                } else {
                    float rr[4] = {r0, r1, r2, r3};
#pragma unroll
                    for (int i = 0; i < 4; ++i)
                        if (p + i < NPOS) op[i] = f2bf(rr[i]);
                }
            } else {
                float* op = (float*)outv + ((size_t)b * C + co) * OSTRIDE + p;
                float rr[4] = {r0, r1, r2, r3};
#pragma unroll
                for (int i = 0; i < 4; ++i)
                    if (p + i < NPOS) op[i] = rr[i];
            }
        }
    }
}

// Depthwise 5x5 valid xcorr: s bf16 [g,C,844], k f32 [g,C,28] -> out f32 [g,C,625].
__global__ __launch_bounds__(256) void xcorr_dw(
    const unsigned short* __restrict__ s, const float* __restrict__ k,
    float* __restrict__ out)
{
    const int bc = blockIdx.x;
    const unsigned short* sp = s + (size_t)bc * 844;
    const float* kp = k + (size_t)bc * 28;
    float* op = out + (size_t)bc * 625;

    __shared__ float s_s[844];
    __shared__ float s_k[25];
    const int t = threadIdx.x;
    if (t < 211) {                       // 211*4 = 844 shorts (incl. pad)
        ushort4 v = *(const ushort4*)(sp + 4 * t);
        s_s[4 * t + 0] = bf2f(v.x);
        s_s[4 * t + 1] = bf2f(v.y);
        s_s[4 * t + 2] = bf2f(v.z);
        s_s[4 * t + 3] = bf2f(v.w);
    }
    if (t < 25) s_k[t] = kp[t];
    __syncthreads();

    float kk[25];
#pragma unroll
    for (int i = 0; i < 25; ++i) kk[i] = s_k[i];

#pragma unroll
    for (int j = 0; j < 3; ++j) {
        int pos = t + j * 256;
        if (pos < 625) {
            int y = pos / 25, x = pos - y * 25;
            float a = 0.f;
#pragma unroll
            for (int dy = 0; dy < 5; ++dy)
#pragma unroll
                for (int dx = 0; dx < 5; ++dx)
                    a += s_s[(y + dy) * 29 + x + dx] * kk[dy * 5 + dx];
            op[pos] = a;
        }
    }
}

extern "C" void kernel_launch(void* const* d_in, const int* in_sizes, int n_in,
                              void* d_out, int out_size, void* d_ws, size_t ws_size,
                              hipStream_t stream) {
    const float* kin = (const float*)d_in[0];   // [128,256,7,7]
    const float* sin_ = (const float*)d_in[1];  // [128,256,31,31]
    const float* wk = (const float*)d_in[2];
    const float* bkg = (const float*)d_in[3];
    const float* bkb = (const float*)d_in[4];
    const float* bkm = (const float*)d_in[5];
    const float* bkv = (const float*)d_in[6];
    const float* ws_ = (const float*)d_in[7];
    const float* bsg = (const float*)d_in[8];
    const float* bsb = (const float*)d_in[9];
    const float* bsm = (const float*)d_in[10];
    const float* bsv = (const float*)d_in[11];
    float* out = (float*)d_out;

    char* base = (char*)d_ws;
    unsigned short* wkt = (unsigned short*)base;               // 1,179,648 B
    unsigned short* wst = wkt + (size_t)9 * C * C;
    char* gbase = base + 2359296;

    const size_t perb_is = (size_t)961 * C * 2;  // 492032
    const size_t perb_ik = (size_t)49 * C * 2;   // 25088
    const size_t perb_sb = (size_t)844 * C * 2;  // 432128
    const size_t perb_kb = (size_t)28 * C * 4;   // 28672
    const size_t perb = perb_is + perb_ik + perb_sb + perb_kb; // 977920

    int G = (int)((ws_size - 2359296) / perb);
    if (G > 128) G = 128;
    G &= ~1;
    if (G < 2) G = 2;

    unsigned short* ips  = (unsigned short*)gbase;
    unsigned short* ipk  = (unsigned short*)(gbase + (size_t)G * perb_is);
    unsigned short* sbuf = (unsigned short*)(gbase + (size_t)G * (perb_is + perb_ik));
    float*          kbuf = (float*)(gbase + (size_t)G * (perb_is + perb_ik + perb_sb));

    wprep<<<C, 256, 0, stream>>>(wk, bkg, bkv, wkt);
    wprep<<<C, 256, 0, stream>>>(ws_, bsg, bsv, wst);

    for (int g0 = 0; g0 < 128; g0 += G) {
        const int g = (128 - g0) < G ? (128 - g0) : G;

        nchw_to_pc<961><<<dim3(16, 4, g), 256, 0, stream>>>(
            sin_ + (size_t)g0 * C * 961, ips);
        nchw_to_pc<49><<<dim3(1, 4, g), 256, 0, stream>>>(
            kin + (size_t)g0 * C * 49, ipk);

        // kernel conv: 7x7 -> 5x5. BPB=2, BM=64, BN=128, MF=2, NF=4, f32 out.
        conv3_mfma<7, 5, 2, 64, 128, 2, 4, false, 28>
            <<<dim3(2, g / 2), 256, 0, stream>>>(ipk, wkt, bkg, bkb, bkm, bkv, kbuf);

        // search conv v3: A-direct-from-L1, B in LDS. 512 thr, BM=224, BN=256.
        sconv_mfma<<<dim3(4, g), 512, 0, stream>>>(
            ips, wst, bsg, bsb, bsm, bsv, sbuf);

        xcorr_dw<<<(unsigned)g * C, 256, 0, stream>>>(sbuf, kbuf, out + (size_t)g0 * C * 625);
    }
}

// Round 8
// 312.654 us; speedup vs baseline: 2.1134x; 2.1134x over previous
//
#include <hip/hip_runtime.h>
#include <hip/hip_bf16.h>

#define BN_EPS 1e-5f
constexpr int C = 256;

typedef __attribute__((ext_vector_type(8))) short bf16x8;
typedef __attribute__((ext_vector_type(4))) float f32x4;

static __device__ __forceinline__ unsigned short f2bf(float f) {
    __hip_bfloat16 h = __float2bfloat16(f);
    return *reinterpret_cast<unsigned short*>(&h);
}
static __device__ __forceinline__ float bf2f(unsigned short u) {
    unsigned int v = ((unsigned int)u) << 16;
    return __uint_as_float(v);
}

// Fold BN scale into weights, transpose [N][C][9] f32 -> [9][N][C] bf16.
__global__ __launch_bounds__(256) void wprep(
    const float* __restrict__ w, const float* __restrict__ gamma,
    const float* __restrict__ var, unsigned short* __restrict__ wt)
{
    const int n = blockIdx.x, c = threadIdx.x;
    const float scale = gamma[n] * rsqrtf(var[n] + BN_EPS);
    const float* wp = w + ((size_t)n * C + c) * 9;
#pragma unroll
    for (int k = 0; k < 9; ++k)
        wt[((size_t)k * C + n) * C + c] = f2bf(wp[k] * scale);
}

// fp32 NCHW [g][C][HW] -> bf16 [g][HW][C] (pixel-major, channel-contiguous).
template<int HW>
__global__ __launch_bounds__(256) void nchw_to_pc(
    const float* __restrict__ in, unsigned short* __restrict__ out)
{
    __shared__ float s_t[64][65];
    const int b = blockIdx.z, c0 = blockIdx.y * 64, px0 = blockIdx.x * 64;
    const int t = threadIdx.x;
    const float* ip = in + ((size_t)b * C + c0) * HW;

#pragma unroll
    for (int it = 0; it < 4; ++it) {
        int i = t + it * 256;
        int cl = i >> 4, q = i & 15;
#pragma unroll
        for (int j = 0; j < 4; ++j) {
            int p = px0 + q * 4 + j;
            s_t[cl][q * 4 + j] = (p < HW) ? ip[(size_t)cl * HW + p] : 0.f;
        }
    }
    __syncthreads();

    unsigned short* op = out + (size_t)b * HW * C + (size_t)px0 * C + c0;
#pragma unroll
    for (int it = 0; it < 2; ++it) {
        int i = t + it * 256;
        int pl = i >> 3, gq = i & 7;
        if (px0 + pl < HW) {
            bf16x8 pk;
#pragma unroll
            for (int u = 0; u < 8; ++u)
                pk[u] = (short)f2bf(s_t[gq * 8 + u][pl]);
            *(bf16x8*)&op[(size_t)pl * C + gq * 8] = pk;
        }
    }
}

// ---------------------------------------------------------------------------
// SEARCH CONV v4 (r5 skeleton + paired-step barriers + deep prefetch):
// 31x31 -> 29x29 implicit-GEMM bf16 MFMA. A and B both staged in LDS.
// Block: 512 thr = 8 waves (2 wm x 4 wn). BM=224, BN=256, wave tile 112x64.
// K-steps s = 0..71 (chunk = s/9, tap = s%9). B: 4 buffers, barrier every
// TWO steps (read buffers {s0%4, s1%4}, write {s0+2, s1+2} — disjoint mod 4).
// B loads for pair i+1 issued at top of pair i (full-pair latency cover).
// A: 2 buffers; loads issued at chunk-crossing pair, written at s%9==7 pair.
// ---------------------------------------------------------------------------
__global__ __launch_bounds__(512, 2) void sconv_mfma(
    const unsigned short* __restrict__ in,   // [g][961][256] bf16
    const unsigned short* __restrict__ wt,   // [9][256][256] bf16
    const float* __restrict__ gamma, const float* __restrict__ beta,
    const float* __restrict__ mean, const float* __restrict__ var,
    unsigned short* __restrict__ outp)       // [g][256][844] bf16
{
    constexpr int WOUT = 29, NPOS = 841;
    constexpr int BM = 224, MF = 7, NF = 4;
    constexpr int LDK = 40;                  // 32 ch + 8 pad (80B rows)
    constexpr int ROWS = 11;
    constexpr int APIX = ROWS * 31;          // 341
    constexpr int ABUF = APIX * LDK;         // 13640 shorts
    constexpr int BBUF = 256 * LDK;          // 10240 shorts
    constexpr int AIT = 3;                   // ceil(341*4 / 512)
    constexpr int BIT = 2;                   // 256*4 / 512

    __shared__ __align__(16) short s_a[2 * ABUF];   //  54,560 B
    __shared__ __align__(16) short s_b[4 * BBUF];   //  81,920 B  (total 136 KB)

    const int t = threadIdx.x;
    const int lane = t & 63, wave = t >> 6;
    const int wm = wave >> 2, wn = wave & 3;
    const int lr = lane >> 4, lc = lane & 15;

    const int p0 = blockIdx.x * BM;          // 0,224,448,672
    const int b  = blockIdx.y;
    const int y0 = p0 / WOUT;
    const int R  = min(ROWS, 31 - y0);
    const int npix = R * 31;

    const unsigned short* in_b = in + (size_t)b * (961 * 256);

    // A fragment bases (short index within an A buffer, dy=dx=0)
    int arow[MF];
#pragma unroll
    for (int m = 0; m < MF; ++m) {
        int pm = wm * 112 + m * 16 + lc;
        int p = p0 + pm; p = p < NPOS ? p : NPOS - 1;
        int y = p / WOUT, x = p - y * WOUT;
        arow[m] = ((y - y0) * 31 + x) * LDK + lr * 8;
    }

    // staging decomposition
    const unsigned short* aptr[AIT]; int aoff[AIT];
#pragma unroll
    for (int it = 0; it < AIT; ++it) {
        int i = t + it * 512;
        int px = i >> 2, sl = i & 3;
        px = px < npix ? px : 0;             // idempotent dup of slot 0
        aptr[it] = in_b + (size_t)(y0 * 31 + px) * 256 + sl * 8;
        aoff[it] = px * LDK + sl * 8;
    }
    const unsigned short* bptr[BIT]; int boff[BIT];
#pragma unroll
    for (int it = 0; it < BIT; ++it) {
        int i = t + it * 512;
        int n = i >> 2, sl = i & 3;
        bptr[it] = wt + (size_t)n * 256 + sl * 8;
        boff[it] = n * LDK + sl * 8;
    }

    f32x4 acc[MF][NF];
#pragma unroll
    for (int m = 0; m < MF; ++m)
#pragma unroll
        for (int n = 0; n < NF; ++n) acc[m][n] = f32x4{0.f, 0.f, 0.f, 0.f};

    bf16x8 bstg0[BIT], bstg1[BIT], astg[AIT];

    // ---- prologue: stage B steps 0,1 and A chunk 0 ----
#pragma unroll
    for (int it = 0; it < BIT; ++it) bstg0[it] = *(const bf16x8*)(bptr[it]);
#pragma unroll
    for (int it = 0; it < BIT; ++it) bstg1[it] = *(const bf16x8*)(bptr[it] + 65536);
#pragma unroll
    for (int it = 0; it < AIT; ++it) astg[it] = *(const bf16x8*)(aptr[it]);
#pragma unroll
    for (int it = 0; it < BIT; ++it) *(bf16x8*)&s_b[boff[it]] = bstg0[it];
#pragma unroll
    for (int it = 0; it < BIT; ++it) *(bf16x8*)&s_b[BBUF + boff[it]] = bstg1[it];
#pragma unroll
    for (int it = 0; it < AIT; ++it) *(bf16x8*)&s_a[aoff[it]] = astg[it];
    __syncthreads();

#define DO_STEP(S)                                                             \
    {                                                                          \
        const int tap_ = (S) % 9;                                              \
        const int dt_ = (tap_ / 3) * 31 + (tap_ % 3);                          \
        const int ab_ = (((S) / 9) & 1) * ABUF;                                \
        const int bb_ = ((S) & 3) * BBUF;                                      \
        bf16x8 bfr[NF], af[MF];                                                \
        _Pragma("unroll")                                                      \
        for (int n = 0; n < NF; ++n)                                           \
            bfr[n] = *(const bf16x8*)&s_b[bb_ + (wn * 64 + n * 16 + lc) * LDK + lr * 8]; \
        _Pragma("unroll")                                                      \
        for (int m = 0; m < MF; ++m)                                           \
            af[m] = *(const bf16x8*)&s_a[ab_ + arow[m] + dt_ * LDK];           \
        _Pragma("unroll")                                                      \
        for (int m = 0; m < MF; ++m)                                           \
            _Pragma("unroll")                                                  \
            for (int n = 0; n < NF; ++n)                                       \
                acc[m][n] = __builtin_amdgcn_mfma_f32_16x16x32_bf16(           \
                    af[m], bfr[n], acc[m][n], 0, 0, 0);                        \
    }

#pragma unroll 1
    for (int pr = 0; pr < 36; ++pr) {
        const int s0 = 2 * pr, s1 = s0 + 1;

        // ---- pair-top issues (land during this pair's compute) ----
        if (pr < 35) {
            const int u0 = s0 + 2, u1 = s1 + 2;
            const int t0 = u0 % 9, c0_ = (u0 / 9) * 32;
            const int t1 = u1 % 9, c1_ = (u1 / 9) * 32;
#pragma unroll
            for (int it = 0; it < BIT; ++it)
                bstg0[it] = *(const bf16x8*)(bptr[it] + (size_t)t0 * 65536 + c0_);
#pragma unroll
            for (int it = 0; it < BIT; ++it)
                bstg1[it] = *(const bf16x8*)(bptr[it] + (size_t)t1 * 65536 + c1_);
        }
        {
            const int cb = (s0 % 9 == 0) ? s0 / 9 : ((s1 % 9 == 0) ? s1 / 9 : -1);
            if (cb >= 0 && cb < 7) {
                const int co_ = (cb + 1) * 32;
#pragma unroll
                for (int it = 0; it < AIT; ++it)
                    astg[it] = *(const bf16x8*)(aptr[it] + co_);
            }
        }

        // ---- two compute steps ----
        DO_STEP(s0)
        DO_STEP(s1)

        // ---- pair-end LDS writes ----
        if (pr < 35) {
            const int w0 = ((s0 + 2) & 3) * BBUF, w1 = ((s1 + 2) & 3) * BBUF;
#pragma unroll
            for (int it = 0; it < BIT; ++it)
                *(bf16x8*)&s_b[w0 + boff[it]] = bstg0[it];
#pragma unroll
            for (int it = 0; it < BIT; ++it)
                *(bf16x8*)&s_b[w1 + boff[it]] = bstg1[it];
        }
        {
            const int cw = (s0 % 9 == 7) ? s0 / 9 : ((s1 % 9 == 7) ? s1 / 9 : -1);
            if (cw >= 0 && cw < 7) {
                const int dst = ((cw & 1) ^ 1) * ABUF;
#pragma unroll
                for (int it = 0; it < AIT; ++it)
                    *(bf16x8*)&s_a[dst + aoff[it]] = astg[it];
            }
        }
        __syncthreads();
    }
#undef DO_STEP

    // ---- epilogue: bias + relu -> bf16 planes (padded stride 844) ----
#pragma unroll
    for (int n = 0; n < NF; ++n) {
        const int co = wn * 64 + n * 16 + lc;
        const float sc = gamma[co] * rsqrtf(var[co] + BN_EPS);
        const float bias = beta[co] - mean[co] * sc;
#pragma unroll
        for (int m = 0; m < MF; ++m) {
            int pm = wm * 112 + m * 16 + lr * 4;
            int p = p0 + pm;
            f32x4 v = acc[m][n];
            float r0 = fmaxf(v.x + bias, 0.f);
            float r1 = fmaxf(v.y + bias, 0.f);
            float r2 = fmaxf(v.z + bias, 0.f);
            float r3 = fmaxf(v.w + bias, 0.f);
            unsigned short* op = outp + ((size_t)b * C + co) * 844 + p;
            if (p + 4 <= NPOS) {
                ushort4 pk;
                pk.x = f2bf(r0); pk.y = f2bf(r1); pk.z = f2bf(r2); pk.w = f2bf(r3);
                *(ushort4*)op = pk;
            } else {
                float rr[4] = {r0, r1, r2, r3};
#pragma unroll
                for (int i = 0; i < 4; ++i)
                    if (p + i < NPOS) op[i] = f2bf(rr[i]);
            }
        }
    }
}

// ---------------------------------------------------------------------------
// KERNEL CONV (small, 7x7 -> 5x5): B from global, A async-staged in LDS.
// ---------------------------------------------------------------------------
template<int HIN, int WOUT, int BPB, int BM, int BN_, int MF, int NF, bool OUT_BF16, int OSTRIDE>
__global__ __launch_bounds__(256, 3) void conv3_mfma(
    const unsigned short* __restrict__ in,
    const unsigned short* __restrict__ wt,
    const float* __restrict__ gamma, const float* __restrict__ beta,
    const float* __restrict__ mean, const float* __restrict__ var,
    void* __restrict__ outv)
{
    constexpr int WIN = HIN, HW = HIN * WIN;
    constexpr int NPOS = WOUT * WOUT;
    constexpr int PPB = BM / BPB;
    constexpr int NMT = (NPOS + PPB - 1) / PPB;
    constexpr int NR0 = (PPB - 1) / WOUT + 4;
    constexpr int NROWS = NR0 < HIN ? NR0 : HIN;
    constexpr int APIX = NROWS * WIN;
    constexpr int LDK = 40;
    constexpr int SLOTS_B = APIX * 4;
    constexpr int SLOTS = BPB * SLOTS_B;
    constexpr int ITERS = (SLOTS + 255) / 256;

    __shared__ __align__(16) short s_a[BPB * APIX * LDK];

    const int t = threadIdx.x;
    const int lane = t & 63, wave = t >> 6;
    const int wm = wave >> 1, wn = wave & 1;
    const int lr = lane >> 4, lc = lane & 15;

    const int mt = blockIdx.x % NMT, nt = blockIdx.x / NMT;
    const int p0 = mt * PPB, n0 = nt * BN_;
    const int b0 = blockIdx.y * BPB;
    const int y0 = p0 / WOUT;
    const int R = (HIN - y0) < NROWS ? (HIN - y0) : NROWS;
    const int npix = R * WIN;

    int arow[MF];
#pragma unroll
    for (int m = 0; m < MF; ++m) {
        int pm = wm * MF * 16 + m * 16 + lc;
        int bb = pm / PPB;
        int p = p0 + (pm % PPB);
        p = p < NPOS ? p : NPOS - 1;
        int y = p / WOUT, x = p % WOUT;
        arow[m] = (bb * APIX + (y - y0) * WIN + x) * LDK;
    }

    f32x4 acc[MF][NF];
#pragma unroll
    for (int m = 0; m < MF; ++m)
#pragma unroll
        for (int n = 0; n < NF; ++n) acc[m][n] = f32x4{0.f, 0.f, 0.f, 0.f};

    int sbb[ITERS], spx[ITERS], ssl[ITERS];
#pragma unroll
    for (int it = 0; it < ITERS; ++it) {
        int i = t + it * 256;
        int ii = i < SLOTS ? i : 0;
        int bb = (BPB == 1) ? 0 : (ii / SLOTS_B);
        int r = ii - bb * SLOTS_B;
        int px = r >> 2;
        sbb[it] = bb; spx[it] = px < npix ? px : 0; ssl[it] = r & 3;
    }

    const unsigned short* wb = wt + (size_t)(n0 + wn * (NF * 16) + lc) * C + lr * 8;

#define LOAD_STG(c0_)                                                          \
    _Pragma("unroll")                                                          \
    for (int it = 0; it < ITERS; ++it) {                                       \
        const unsigned short* sp =                                             \
            in + ((size_t)(b0 + sbb[it]) * HW + (size_t)(y0 * WIN + spx[it])) * C \
               + (c0_) + ssl[it] * 8;                                          \
        stg[it] = *(const bf16x8*)sp;                                          \
    }

#define WRITE_STG()                                                            \
    _Pragma("unroll")                                                          \
    for (int it = 0; it < ITERS; ++it)                                         \
        *(bf16x8*)&s_a[(sbb[it] * APIX + spx[it]) * LDK + ssl[it] * 8] = stg[it];

    {
        bf16x8 stg[ITERS];
        LOAD_STG(0)
        WRITE_STG()
    }

#pragma unroll 1
    for (int ch = 0; ch < 8; ++ch) {
        const int c0 = ch * 32;
        __syncthreads();

        bf16x8 stg[ITERS];
        if (ch < 7) { LOAD_STG(c0 + 32) }

        bf16x8 bcur[NF], bnxt[NF];
#pragma unroll
        for (int n = 0; n < NF; ++n)
            bnxt[n] = *(const bf16x8*)&wb[0 * (size_t)(C * C) + n * (16 * C) + c0];

#pragma unroll
        for (int tap = 0; tap < 9; ++tap) {
            const int dy = tap / 3, dx = tap % 3;
#pragma unroll
            for (int n = 0; n < NF; ++n) bcur[n] = bnxt[n];
            if (tap < 8) {
#pragma unroll
                for (int n = 0; n < NF; ++n)
                    bnxt[n] = *(const bf16x8*)&wb[(size_t)(tap + 1) * (C * C) + n * (16 * C) + c0];
            }
            bf16x8 af[MF];
#pragma unroll
            for (int m = 0; m < MF; ++m)
                af[m] = *(const bf16x8*)&s_a[arow[m] + (dy * WIN + dx) * LDK + lr * 8];
#pragma unroll
            for (int m = 0; m < MF; ++m)
#pragma unroll
                for (int n = 0; n < NF; ++n)
                    acc[m][n] = __builtin_amdgcn_mfma_f32_16x16x32_bf16(
                        af[m], bcur[n], acc[m][n], 0, 0, 0);
        }

        __syncthreads();
        if (ch < 7) { WRITE_STG() }
    }
#undef LOAD_STG
#undef WRITE_STG

#pragma unroll
    for (int n = 0; n < NF; ++n) {
        const int co = n0 + wn * NF * 16 + n * 16 + lc;
        const float sc = gamma[co] * rsqrtf(var[co] + BN_EPS);
        const float bias = beta[co] - mean[co] * sc;
#pragma unroll
        for (int m = 0; m < MF; ++m) {
            int pm = wm * MF * 16 + m * 16 + lr * 4;
            int bb = pm / PPB;
            int p = p0 + (pm % PPB);
            int b = b0 + bb;
            f32x4 v = acc[m][n];
            float r0 = fmaxf(v.x + bias, 0.f);
            float r1 = fmaxf(v.y + bias, 0.f);
            float r2 = fmaxf(v.z + bias, 0.f);
            float r3 = fmaxf(v.w + bias, 0.f);
            if (OUT_BF16) {
                unsigned short* op = (unsigned short*)outv + ((size_t)b * C + co) * OSTRIDE + p;
                if (p + 4 <= NPOS) {
                    ushort4 pk;
                    pk.x = f2bf(r0); pk.y = f2bf(r1); pk.z = f2bf(r2); pk.w = f2bf(r3);
                    *(ushort4*)op = pk;
                } else {
                    float rr[4] = {r0, r1, r2, r3};
#pragma unroll
                    for (int i = 0; i < 4; ++i)
                        if (p + i < NPOS) op[i] = f2bf(rr[i]);
                }
            } else {
                float* op = (float*)outv + ((size_t)b * C + co) * OSTRIDE + p;
                float rr[4] = {r0, r1, r2, r3};
#pragma unroll
                for (int i = 0; i < 4; ++i)
                    if (p + i < NPOS) op[i] = rr[i];
            }
        }
    }
}

// Depthwise 5x5 valid xcorr: s bf16 [g,C,844], k f32 [g,C,28] -> out f32 [g,C,625].
__global__ __launch_bounds__(256) void xcorr_dw(
    const unsigned short* __restrict__ s, const float* __restrict__ k,
    float* __restrict__ out)
{
    const int bc = blockIdx.x;
    const unsigned short* sp = s + (size_t)bc * 844;
    const float* kp = k + (size_t)bc * 28;
    float* op = out + (size_t)bc * 625;

    __shared__ float s_s[844];
    __shared__ float s_k[25];
    const int t = threadIdx.x;
    if (t < 211) {                       // 211*4 = 844 shorts (incl. pad)
        ushort4 v = *(const ushort4*)(sp + 4 * t);
        s_s[4 * t + 0] = bf2f(v.x);
        s_s[4 * t + 1] = bf2f(v.y);
        s_s[4 * t + 2] = bf2f(v.z);
        s_s[4 * t + 3] = bf2f(v.w);
    }
    if (t < 25) s_k[t] = kp[t];
    __syncthreads();

    float kk[25];
#pragma unroll
    for (int i = 0; i < 25; ++i) kk[i] = s_k[i];

#pragma unroll
    for (int j = 0; j < 3; ++j) {
        int pos = t + j * 256;
        if (pos < 625) {
            int y = pos / 25, x = pos - y * 25;
            float a = 0.f;
#pragma unroll
            for (int dy = 0; dy < 5; ++dy)
#pragma unroll
                for (int dx = 0; dx < 5; ++dx)
                    a += s_s[(y + dy) * 29 + x + dx] * kk[dy * 5 + dx];
            op[pos] = a;
        }
    }
}

extern "C" void kernel_launch(void* const* d_in, const int* in_sizes, int n_in,
                              void* d_out, int out_size, void* d_ws, size_t ws_size,
                              hipStream_t stream) {
    const float* kin = (const float*)d_in[0];   // [128,256,7,7]
    const float* sin_ = (const float*)d_in[1];  // [128,256,31,31]
    const float* wk = (const float*)d_in[2];
    const float* bkg = (const float*)d_in[3];
    const float* bkb = (const float*)d_in[4];
    const float* bkm = (const float*)d_in[5];
    const float* bkv = (const float*)d_in[6];
    const float* ws_ = (const float*)d_in[7];
    const float* bsg = (const float*)d_in[8];
    const float* bsb = (const float*)d_in[9];
    const float* bsm = (const float*)d_in[10];
    const float* bsv = (const float*)d_in[11];
    float* out = (float*)d_out;

    char* base = (char*)d_ws;
    unsigned short* wkt = (unsigned short*)base;               // 1,179,648 B
    unsigned short* wst = wkt + (size_t)9 * C * C;
    char* gbase = base + 2359296;

    const size_t perb_is = (size_t)961 * C * 2;  // 492032
    const size_t perb_ik = (size_t)49 * C * 2;   // 25088
    const size_t perb_sb = (size_t)844 * C * 2;  // 432128
    const size_t perb_kb = (size_t)28 * C * 4;   // 28672
    const size_t perb = perb_is + perb_ik + perb_sb + perb_kb; // 977920

    int G = (int)((ws_size - 2359296) / perb);
    if (G > 128) G = 128;
    G &= ~1;
    if (G < 2) G = 2;

    unsigned short* ips  = (unsigned short*)gbase;
    unsigned short* ipk  = (unsigned short*)(gbase + (size_t)G * perb_is);
    unsigned short* sbuf = (unsigned short*)(gbase + (size_t)G * (perb_is + perb_ik));
    float*          kbuf = (float*)(gbase + (size_t)G * (perb_is + perb_ik + perb_sb));

    wprep<<<C, 256, 0, stream>>>(wk, bkg, bkv, wkt);
    wprep<<<C, 256, 0, stream>>>(ws_, bsg, bsv, wst);

    for (int g0 = 0; g0 < 128; g0 += G) {
        const int g = (128 - g0) < G ? (128 - g0) : G;

        nchw_to_pc<961><<<dim3(16, 4, g), 256, 0, stream>>>(
            sin_ + (size_t)g0 * C * 961, ips);
        nchw_to_pc<49><<<dim3(1, 4, g), 256, 0, stream>>>(
            kin + (size_t)g0 * C * 49, ipk);

        // kernel conv: 7x7 -> 5x5. BPB=2, BM=64, BN=128, MF=2, NF=4, f32 out.
        conv3_mfma<7, 5, 2, 64, 128, 2, 4, false, 28>
            <<<dim3(2, g / 2), 256, 0, stream>>>(ipk, wkt, bkg, bkb, bkm, bkv, kbuf);

        // search conv v4: paired-step barriers, 4x B-buffer, deep prefetch.
        sconv_mfma<<<dim3(4, g), 512, 0, stream>>>(
            ips, wst, bsg, bsb, bsm, bsv, sbuf);

        xcorr_dw<<<(unsigned)g * C, 256, 0, stream>>>(sbuf, kbuf, out + (size_t)g0 * C * 625);
    }
}